// Round 16
// baseline (196.168 us; speedup 1.0000x reference)
//
#include <hip/hip_runtime.h>
#include <hip/hip_bf16.h>
#include <stdint.h>

typedef unsigned short u16;
typedef __attribute__((ext_vector_type(8))) short bf16x8;   // 8 bf16 in 4 VGPRs
typedef __attribute__((ext_vector_type(4))) float f32x4;

__device__ __forceinline__ u16 f2bf(float f) {
    union { float f; unsigned int i; } c; c.f = f;
    unsigned int x = c.i;
    return (u16)((x + 0x7FFFu + ((x >> 16) & 1u)) >> 16);   // RNE
}
__device__ __forceinline__ u16 f2bf_fast(float f) {         // tie-away, 2 VALU
    union { float f; unsigned int i; } c; c.f = f;
    return (u16)((c.i + 0x8000u) >> 16);
}

// async global->LDS, 16B per lane; LDS dst = uniform base + lane*16
__device__ __forceinline__ void glds16(const u16* g, u16* l) {
    __builtin_amdgcn_global_load_lds(
        (const __attribute__((address_space(1))) void*)g,
        (__attribute__((address_space(3))) void*)l, 16, 0, 0);
}

// manual sync: raw barrier + partial vmcnt waits. LESSON (r13/r14): only
// glds staging (vmcnt-tracked) may publish LDS across waves with these;
// cross-wave ds_write publication raced even with lgkmcnt(0) — banned.
__device__ __forceinline__ void bar() { asm volatile("s_barrier" ::: "memory"); }
template <int N> __device__ __forceinline__ void waitv() {
    if constexpr (N == 0)      asm volatile("s_waitcnt vmcnt(0)" ::: "memory");
    else if constexpr (N == 2) asm volatile("s_waitcnt vmcnt(2)" ::: "memory");
    else if constexpr (N == 3) asm volatile("s_waitcnt vmcnt(3)" ::: "memory");
    else if constexpr (N == 4) asm volatile("s_waitcnt vmcnt(4)" ::: "memory");
}

// ---------------------------------------------------------------------------
// fp32 -> bf16 conversion of z, wq, wk, wv, wo (one kernel, 8 elems/thread)
// ---------------------------------------------------------------------------
__global__ __launch_bounds__(256) void convert_all(
    const float* __restrict__ z, const float* __restrict__ wq,
    const float* __restrict__ wk, const float* __restrict__ wv,
    const float* __restrict__ wo,
    u16* __restrict__ zb, u16* __restrict__ wqb, u16* __restrict__ wkb,
    u16* __restrict__ wvb, u16* __restrict__ wob)
{
    int g = blockIdx.x * 256 + threadIdx.x;      // group of 8 elements
    const float* s; u16* d;
    if (g < 786432)       { s = z;  d = zb;  }
    else if (g < 860160)  { s = wq; d = wqb; g -= 786432; }
    else if (g < 933888)  { s = wk; d = wkb; g -= 860160; }
    else if (g < 1007616) { s = wv; d = wvb; g -= 933888; }
    else                  { s = wo; d = wob; g -= 1007616; }
    float4 a = *(const float4*)(s + (size_t)g * 8);
    float4 b = *(const float4*)(s + (size_t)g * 8 + 4);
    u16 t[8] = {f2bf(a.x), f2bf(a.y), f2bf(a.z), f2bf(a.w),
                f2bf(b.x), f2bf(b.y), f2bf(b.z), f2bf(b.w)};
    *(uint4*)(d + (size_t)g * 8) = *(const uint4*)t;
}

// ---------------------------------------------------------------------------
// r9-proven dbuf glds K-loop (one __syncthreads/iter) for oproj (256 thr).
// LDS 16B cells: cell(row,kq) = row*4 + (kq ^ ((row>>1)&3)).
// ---------------------------------------------------------------------------
template <int MI>
__device__ __forceinline__ void gemm_mainloop(
    const u16* __restrict__ A, const u16* __restrict__ B,
    u16* As, u16* Bs, f32x4 (&acc)[MI][4], int m0, int lda, int ldb, int K)
{
    const int t = threadIdx.x;
    const int w = t >> 6, lane = t & 63, quad = lane >> 4, lc = lane & 15;
    const int wm = w >> 1, wn = w & 1;
    const int swz = (lc >> 1) & 3;
    constexpr int NA = MI / 2;
    constexpr int ASZ = 1024 * MI;

    const u16* pa[NA]; int la[NA];
    #pragma unroll
    for (int j = 0; j < NA; j++) {
        const int c = j * 256 + t;
        const int row = c >> 2;
        const int kq = (c & 3) ^ ((row >> 1) & 3);
        pa[j] = &A[(size_t)(m0 + row) * lda + kq * 8];
        la[j] = (j * 256 + w * 64) * 8;
    }
    const u16* pb[2]; int lb[2];
    #pragma unroll
    for (int j = 0; j < 2; j++) {
        const int c = j * 256 + t;
        const int row = c >> 2;
        const int kq = (c & 3) ^ ((row >> 1) & 3);
        pb[j] = &B[(size_t)row * ldb + kq * 8];
        lb[j] = (j * 256 + w * 64) * 8;
    }

    #pragma unroll
    for (int j = 0; j < NA; j++) glds16(pa[j], As + la[j]);
    #pragma unroll
    for (int j = 0; j < 2; j++) glds16(pb[j], Bs + lb[j]);
    __syncthreads();

    int buf = 0;
    for (int k0 = 0; k0 < K; k0 += 32) {
        if (k0 + 32 < K) {
            const int na = (buf ^ 1) * ASZ, nbb = (buf ^ 1) * 4096;
            #pragma unroll
            for (int j = 0; j < NA; j++) glds16(pa[j] + k0 + 32, As + na + la[j]);
            #pragma unroll
            for (int j = 0; j < 2; j++)  glds16(pb[j] + k0 + 32, Bs + nbb + lb[j]);
        }
        bf16x8 af[MI], bfr[4];
        #pragma unroll
        for (int i = 0; i < MI; i++) {
            const int row = 32 * NA * wm + 16 * i + lc;
            af[i] = *(const bf16x8*)&As[buf * ASZ + (row * 4 + (quad ^ swz)) * 8];
        }
        #pragma unroll
        for (int j = 0; j < 4; j++) {
            const int row = 64 * wn + 16 * j + lc;
            bfr[j] = *(const bf16x8*)&Bs[buf * 4096 + (row * 4 + (quad ^ swz)) * 8];
        }
        #pragma unroll
        for (int i = 0; i < MI; i++)
            #pragma unroll
            for (int j = 0; j < 4; j++)
                acc[i][j] = __builtin_amdgcn_mfma_f32_16x16x32_bf16(af[i], bfr[j], acc[i][j], 0, 0, 0);
        __syncthreads();
        buf ^= 1;
    }
}

// ---------------------------------------------------------------------------
// QKV (r15-proven): 256 threads (4 waves 2x2), tile 128x128, BK 32, manual
// 2-bar glds pipeline, XCD-aware 1-D grid (1152): n=d/64, m=d%64 -> XCD=m%8.
// ---------------------------------------------------------------------------
__global__ __launch_bounds__(256) void qkv_gemm(
    const u16* __restrict__ zb, const u16* __restrict__ wqb,
    const u16* __restrict__ wkb, const u16* __restrict__ wvb,
    u16* __restrict__ qkb, u16* __restrict__ vt)
{
    __shared__ __align__(16) u16 As[8192], Bs[8192];   // dbuf: 4096 u16 per buffer
    const int d = blockIdx.x;
    const int n0 = (d >> 6) * 128, m0 = (d & 63) * 128;
    const u16* Bp;
    if (n0 < 768)       Bp = wqb + (size_t)n0 * 768;
    else if (n0 < 1536) Bp = wkb + (size_t)(n0 - 768) * 768;
    else                Bp = wvb + (size_t)(n0 - 1536) * 768;

    const int t = threadIdx.x;
    const int w = t >> 6, lane = t & 63, quad = lane >> 4, lc = lane & 15;
    const int wm = w >> 1, wn = w & 1;
    const int swz = (lc >> 1) & 3;

    const u16* pa[2]; const u16* pb[2]; int la[2], lb[2];
    #pragma unroll
    for (int j = 0; j < 2; j++) {
        const int c = j * 256 + t;
        const int row = c >> 2;
        const int kq = (c & 3) ^ ((row >> 1) & 3);
        pa[j] = &zb[(size_t)(m0 + row) * 768 + kq * 8];
        pb[j] = &Bp[(size_t)row * 768 + kq * 8];
        la[j] = lb[j] = (j * 256 + w * 64) * 8;    // wave-uniform cell base * 8
    }

    // prologue: tile0 -> buf0, tile1 -> buf1 (4 glds per thread per tile)
    glds16(pa[0], As + la[0]);  glds16(pa[1], As + la[1]);
    glds16(pb[0], Bs + lb[0]);  glds16(pb[1], Bs + lb[1]);
    glds16(pa[0] + 32, As + 4096 + la[0]);  glds16(pa[1] + 32, As + 4096 + la[1]);
    glds16(pb[0] + 32, Bs + 4096 + lb[0]);  glds16(pb[1] + 32, Bs + 4096 + lb[1]);

    f32x4 acc[4][4] = {};
    int buf = 0;
    for (int bk = 0; bk < 24; bk++) {
        if (bk + 1 < 24) waitv<4>(); else waitv<0>();   // tile bk landed
        bar();
        bf16x8 af[4], bfr[4];
        #pragma unroll
        for (int i = 0; i < 4; i++) {
            const int row = 64 * wm + 16 * i + lc;
            af[i] = *(const bf16x8*)&As[buf * 4096 + (row * 4 + (quad ^ swz)) * 8];
        }
        #pragma unroll
        for (int j = 0; j < 4; j++) {
            const int row = 64 * wn + 16 * j + lc;
            bfr[j] = *(const bf16x8*)&Bs[buf * 4096 + (row * 4 + (quad ^ swz)) * 8];
        }
        #pragma unroll
        for (int i = 0; i < 4; i++)
            #pragma unroll
            for (int j = 0; j < 4; j++)
                acc[i][j] = __builtin_amdgcn_mfma_f32_16x16x32_bf16(af[i], bfr[j], acc[i][j], 0, 0, 0);
        bar();                          // all waves' frag reads done
        if (bk + 2 < 24) {              // tile bk+2 -> the buffer just read
            const int k2 = (bk + 2) * 32;
            glds16(pa[0] + k2, As + buf * 4096 + la[0]);
            glds16(pa[1] + k2, As + buf * 4096 + la[1]);
            glds16(pb[0] + k2, Bs + buf * 4096 + lb[0]);
            glds16(pb[1] + k2, Bs + buf * 4096 + lb[1]);
        }
        buf ^= 1;
    }

    if (n0 < 1536) {
        #pragma unroll
        for (int i = 0; i < 4; i++)
            #pragma unroll
            for (int j = 0; j < 4; j++) {
                const int col = n0 + 64 * wn + 16 * j + lc;
                #pragma unroll
                for (int r = 0; r < 4; r++) {
                    const int row = m0 + 64 * wm + 16 * i + quad * 4 + r;
                    qkb[(size_t)row * 1536 + col] = f2bf_fast(acc[i][j][r]);
                }
            }
    } else {
        #pragma unroll
        for (int i = 0; i < 4; i++)
            #pragma unroll
            for (int j = 0; j < 4; j++) {
                const int c = (n0 - 1536) + 64 * wn + 16 * j + lc;   // 0..767
                const int h = c >> 6, dd = c & 63;
                const int tok0 = m0 + 64 * wm + 16 * i + quad * 4;
                const int b = tok0 >> 10, n = tok0 & 1023;
                ushort4 pk = { f2bf_fast(acc[i][j][0]), f2bf_fast(acc[i][j][1]),
                               f2bf_fast(acc[i][j][2]), f2bf_fast(acc[i][j][3]) };
                *(ushort4*)&vt[(((size_t)(b * 12 + h)) * 64 + dd) * 1024 + n] = pk;
            }
    }
}

// out[8192,768](f32) = obuf[8192,768](bf16) x wob[768,768]^T + bo
// M-tile 64 (MI=2). XCD-aware 1-D grid (768): n = d/128, m = d%128.
__global__ __launch_bounds__(256) void oproj_gemm(
    const u16* __restrict__ ob, const u16* __restrict__ wob,
    const float* __restrict__ bo, float* __restrict__ out)
{
    __shared__ __align__(16) u16 As[4096], Bs[8192];
    const int d = blockIdx.x;
    const int n0 = (d >> 7) * 128, m0 = (d & 127) * 64;
    f32x4 acc[2][4] = {};
    gemm_mainloop<2>(ob, wob + (size_t)n0 * 768, As, Bs, acc, m0, 768, 768, 768);

    const int t = threadIdx.x;
    const int w = t >> 6, lane = t & 63, quad = lane >> 4, lc = lane & 15;
    const int wm = w >> 1, wn = w & 1;
    #pragma unroll
    for (int i = 0; i < 2; i++)
        #pragma unroll
        for (int j = 0; j < 4; j++) {
            const int col = n0 + 64 * wn + 16 * j + lc;
            const float bv = bo[col];
            #pragma unroll
            for (int r = 0; r < 4; r++) {
                const int row = m0 + 32 * wm + 16 * i + quad * 4 + r;
                out[(size_t)row * 768 + col] = acc[i][j][r] + bv;
            }
        }
}

// ---------------------------------------------------------------------------
// Flash attention, 512 threads = 8 waves; wave w owns q rows [16w,16w+16).
// NEW (r16): dedicated LDS regions Ks(16K)/Vts(16K)/Ph(16K = half P-tile,
// XOR cells, WAVE-PRIVATE rows -> zero sync) so K(kt+1) and V(kt+1) are
// glds-prefetched a phase ahead: K hides behind softmax+PV, V behind next
// QK^T. All cross-wave publication is glds (vmcnt) + bar — the only pattern
// proven safe (r13/r14). PV runs in two half-steps over Ph.
// ---------------------------------------------------------------------------
__global__ __launch_bounds__(512, 4) void attn_kernel(
    const u16* __restrict__ qkb, const u16* __restrict__ vt,
    u16* __restrict__ obuf)
{
    const int b = blockIdx.x / 12, h = blockIdx.x % 12;
    const int q0 = blockIdx.y * 128;
    const int t = threadIdx.x;
    const int w = t >> 6, lane = t & 63, quad = lane >> 4, lc = lane & 15;

    const u16* Qp  = qkb + (size_t)b * 1024 * 1536 + h * 64;
    const u16* Kp  = Qp + 768;
    const u16* Vtp = vt + ((size_t)(b * 12 + h)) * 64 * 1024;

    __shared__ __align__(16) u16 Ks[8192];    // K tile cells (16 KB)
    __shared__ __align__(16) u16 Vts[8192];   // V^T XOR cells (16 KB)
    __shared__ __align__(16) u16 Ph[8192];    // P half-tile 128x64, XOR cells (16 KB)

    // K staging: cells c = j*512 + t; row=c>>3, kq=(c&7)^((row>>1)&7)
    const u16* kp[2]; u16* kl[2];
    #pragma unroll
    for (int j = 0; j < 2; j++) {
        const int c = j * 512 + t;
        const int row = c >> 3;
        const int kq = (c & 7) ^ ((row >> 1) & 7);
        kp[j] = Kp + (size_t)row * 1536 + kq * 8;
        kl[j] = &Ks[(j * 512 + w * 64) * 8];
    }
    // V staging: cells c = s*64 + lane, s = 2w+s2; d=c>>4, kq=(c&15)^(d&15)
    const u16* vp[2]; u16* vl[2];
    #pragma unroll
    for (int s2 = 0; s2 < 2; s2++) {
        const int s = 2 * w + s2;
        const int c = s * 64 + lane;
        const int dd = c >> 4, kq = (c & 15) ^ (dd & 15);
        vp[s2] = Vtp + (size_t)dd * 1024 + kq * 8;
        vl[s2] = &Vts[s * 512];
    }

    // Q fragment (A-layout m=lc): this wave's 16 q rows
    bf16x8 qf[2];
    #pragma unroll
    for (int kk = 0; kk < 2; kk++)
        qf[kk] = *(const bf16x8*)&Qp[(size_t)(q0 + 16 * w + lc) * 1536 + kk * 32 + quad * 8];

    f32x4 oacc[4] = {};
    float lsum[4] = {0.0f, 0.0f, 0.0f, 0.0f};

    const float cs = 0.18033688011112042f;  // log2(e) / sqrt(64)
    const int swk = (lc >> 1) & 7;
    const int q7 = quad * 4;                // + r gives q&15 base (w*16 drops mod 8 in pairs)

    // prologue: issue K(0) then V(0); loop-top waitv<2> drains K(0)
    waitv<0>();                             // qf drained; clean vmcnt
    glds16(kp[0], kl[0]);  glds16(kp[1], kl[1]);
    glds16(vp[0], vl[0]);  glds16(vp[1], vl[1]);

    for (int kt = 0; kt < 8; kt++) {
        waitv<2>();                         // K(kt) landed; V(kt) still in flight
        bar();                              // K visible to all waves

        // S = Q K^T : B frag (n=16j+lc, k=kk*32+quad*8) at cell n*8+(kq^swk)
        f32x4 sacc[8] = {};
        #pragma unroll
        for (int j = 0; j < 8; j++) {
            const int nrow = 16 * j + lc;
            bf16x8 kf0 = *(const bf16x8*)&Ks[(nrow * 8 + (quad ^ swk)) * 8];
            bf16x8 kf1 = *(const bf16x8*)&Ks[(nrow * 8 + ((4 + quad) ^ swk)) * 8];
            sacc[j] = __builtin_amdgcn_mfma_f32_16x16x32_bf16(qf[0], kf0, sacc[j], 0, 0, 0);
            sacc[j] = __builtin_amdgcn_mfma_f32_16x16x32_bf16(qf[1], kf1, sacc[j], 0, 0, 0);
        }
        bar();                              // all waves' K reads done -> Ks free

        if (kt < 7) {                       // prefetch K(kt+1); hides behind softmax+PV
            glds16(kp[0] + (size_t)(kt + 1) * 128 * 1536, kl[0]);
            glds16(kp[1] + (size_t)(kt + 1) * 128 * 1536, kl[1]);
        }

        // softmax half 0 (kc 0..63): P -> Ph (wave-private rows)
        #pragma unroll
        for (int j = 0; j < 4; j++)
            #pragma unroll
            for (int r = 0; r < 4; r++) {
                float p = __builtin_amdgcn_exp2f(sacc[j][r] * cs);
                lsum[r] += p;
                const int qr = 16 * w + q7 + r;
                const int cell = (2 * j + (lc >> 3)) ^ ((q7 + r) & 7);
                Ph[qr * 64 + cell * 8 + (lc & 7)] = f2bf_fast(p);
            }

        if (kt < 7) waitv<2>(); else waitv<0>();  // V(kt) landed; K(kt+1) in flight
        bar();                              // V visible to all waves

        // PV half 0: ks = 0,1 (kc 0..63)
        #pragma unroll
        for (int ks = 0; ks < 2; ks++) {
            bf16x8 pa = *(const bf16x8*)&Ph[((16 * w + lc) * 8 + ((ks * 4 + quad) ^ (lc & 7))) * 8];
            #pragma unroll
            for (int jd = 0; jd < 4; jd++) {
                bf16x8 vb = *(const bf16x8*)&Vts[(((16 * jd + lc) << 4) + ((ks * 4 + quad) ^ lc)) * 8];
                oacc[jd] = __builtin_amdgcn_mfma_f32_16x16x32_bf16(pa, vb, oacc[jd], 0, 0, 0);
            }
        }

        // softmax half 1 (kc 64..127): overwrite Ph (same wave-private rows)
        #pragma unroll
        for (int j2 = 0; j2 < 4; j2++)
            #pragma unroll
            for (int r = 0; r < 4; r++) {
                float p = __builtin_amdgcn_exp2f(sacc[4 + j2][r] * cs);
                lsum[r] += p;
                const int qr = 16 * w + q7 + r;
                const int cell = (2 * j2 + (lc >> 3)) ^ ((q7 + r) & 7);
                Ph[qr * 64 + cell * 8 + (lc & 7)] = f2bf_fast(p);
            }

        // PV half 1: ks = 2,3 (kc 64..127); Ph holds half-1 data (ks2 = ks-2)
        #pragma unroll
        for (int ks = 2; ks < 4; ks++) {
            bf16x8 pa = *(const bf16x8*)&Ph[((16 * w + lc) * 8 + (((ks - 2) * 4 + quad) ^ (lc & 7))) * 8];
            #pragma unroll
            for (int jd = 0; jd < 4; jd++) {
                bf16x8 vb = *(const bf16x8*)&Vts[(((16 * jd + lc) << 4) + ((ks * 4 + quad) ^ lc)) * 8];
                oacc[jd] = __builtin_amdgcn_mfma_f32_16x16x32_bf16(pa, vb, oacc[jd], 0, 0, 0);
            }
        }
        bar();                              // all waves' Vts reads done -> Vts free

        if (kt < 7) {                       // prefetch V(kt+1); hides behind next QK^T
            glds16(vp[0] + (kt + 1) * 128, vl[0]);
            glds16(vp[1] + (kt + 1) * 128, vl[1]);
        }
    }

    // one shuffle-reduce of l across the 16 lanes holding each row
    #pragma unroll
    for (int off = 1; off < 16; off <<= 1)
        #pragma unroll
        for (int r = 0; r < 4; r++)
            lsum[r] += __shfl_xor(lsum[r], off, 64);

    // epilogue: O * (1/l), store bf16 into [B,N,H*Dh]
    float invl[4];
    #pragma unroll
    for (int r = 0; r < 4; r++) invl[r] = __builtin_amdgcn_rcpf(lsum[r]);
    #pragma unroll
    for (int jd = 0; jd < 4; jd++)
        #pragma unroll
        for (int r = 0; r < 4; r++) {
            const int row = q0 + 16 * w + quad * 4 + r;
            const int col = h * 64 + 16 * jd + lc;
            obuf[((size_t)b * 1024 + row) * 768 + col] = f2bf_fast(oacc[jd][r] * invl[r]);
        }
}

extern "C" void kernel_launch(void* const* d_in, const int* in_sizes, int n_in,
                              void* d_out, int out_size, void* d_ws, size_t ws_size,
                              hipStream_t stream) {
    const float* z  = (const float*)d_in[0];
    const float* wq = (const float*)d_in[1];
    const float* wk = (const float*)d_in[2];
    const float* wv = (const float*)d_in[3];
    const float* wo = (const float*)d_in[4];
    const float* bo = (const float*)d_in[5];

    u16* ws16 = (u16*)d_ws;
    u16* zb   = ws16;                 // 6,291,456 u16 (reused as obuf)
    u16* wqb  = zb  + 6291456;        //   589,824 each
    u16* wkb  = wqb + 589824;
    u16* wvb  = wkb + 589824;
    u16* wob  = wvb + 589824;
    u16* vt   = wob + 589824;         // 6,291,456   (total 29.9 MB)
    u16* qkb  = (u16*)d_out;          // 12,582,912 u16 == d_out bytes; dead before oproj
    u16* obuf = zb;                   // zb dead after qkv_gemm
    float* out = (float*)d_out;

    convert_all<<<4224, 256, 0, stream>>>(z, wq, wk, wv, wo, zb, wqb, wkb, wvb, wob);
    qkv_gemm<<<1152, 256, 0, stream>>>(zb, wqb, wkb, wvb, qkb, vt);
    attn_kernel<<<dim3(96, 8), 512, 0, stream>>>(qkb, vt, obuf);
    oproj_gemm<<<768, 256, 0, stream>>>(obuf, wob, bo, out);
}